// Round 6
// baseline (9941.118 us; speedup 1.0000x reference)
//
#include <hip/hip_runtime.h>

#define BB 32
#define NN 16384
#define CC 64
#define NC 4096
#define T  1024          // threads per FPS block
#define SLOTS (NN / T)   // 16 points per thread

// ---------------------------------------------------------------------------
// FPS kernel: one block per batch element. Points + running dists in regs.
// Distance chain B1 = fma(dz,dz, fma(dx,dx, dy*dy)) — the x86 DAG-combiner
// contraction XLA-CPU fast-math emits for sum((p-c)^2, -1).
// contract(off) pragma prevents any OTHER contraction; fmaf is explicit.
// Emission: pre-update ([0, nxt_0, ...]) — confirmed correct by R4's
// bf16-decoded poison datum. Winning index per iteration written into d_out
// (one int per output row); gather kernel reads it before overwriting.
// ---------------------------------------------------------------------------
__global__ __launch_bounds__(T) void fps_kernel(const float* __restrict__ in,
                                                float* __restrict__ out) {
#pragma clang fp contract(off)
    const int b    = blockIdx.x;
    const int t    = threadIdx.x;
    const int wave = t >> 6;
    const int lane = t & 63;

    __shared__ float s_val[16];
    __shared__ int   s_idx[16];
    __shared__ float s_cx, s_cy, s_cz;
    __shared__ int   s_far;

    const float* base = in + (size_t)b * NN * CC;

    float px[SLOTS], py[SLOTS], pz[SLOTS], dist[SLOTS];
#pragma unroll
    for (int j = 0; j < SLOTS; ++j) {
        const int i = j * T + t;
        const float4 v = *reinterpret_cast<const float4*>(base + (size_t)i * CC);
        px[j] = v.x; py[j] = v.y; pz[j] = v.z;
        dist[j] = 1e10f;
    }

    if (t == 0) {
        s_far = 0;
        s_cx = px[0]; s_cy = py[0]; s_cz = pz[0];   // point 0 == slot 0 of thread 0
    }
    __syncthreads();

    int* idx_out = reinterpret_cast<int*>(out);

    for (int it = 0; it < NC; ++it) {
        const int   fa = s_far;
        const float cx = s_cx, cy = s_cy, cz = s_cz;
        if (t == 0) idx_out[((size_t)b * NC + it) * CC] = fa;
        if (it == NC - 1) break;

        // ---- dist update + thread-local argmax ----
        // Slot indices ascend with j, so `nd > lv` keeps the first
        // occurrence on exact ties (numpy argmax semantics).
        float lv = -1.0f;
        int   li = 0;
#pragma unroll
        for (int j = 0; j < SLOTS; ++j) {
            const float dx = px[j] - cx;
            const float dy = py[j] - cy;
            const float dz = pz[j] - cz;
            const float d  = fmaf(dz, dz, fmaf(dx, dx, dy * dy));   // chain B1
            const float nd = fminf(dist[j], d);
            dist[j] = nd;
            const bool better = (nd > lv);
            lv = better ? nd : lv;
            li = better ? (j * T + t) : li;
        }

        // ---- wave64 reduce (val, idx), lower index wins ties ----
#pragma unroll
        for (int off = 32; off > 0; off >>= 1) {
            const float ov = __shfl_down(lv, off);
            const int   oi = __shfl_down(li, off);
            const bool better = (ov > lv) || (ov == lv && oi < li);
            lv = better ? ov : lv;
            li = better ? oi : li;
        }
        if (lane == 0) { s_val[wave] = lv; s_idx[wave] = li; }
        __syncthreads();

        // ---- block reduce over 16 wave leaders (thread 0) ----
        if (t == 0) {
            float bv = s_val[0];
            int   bi = s_idx[0];
#pragma unroll
            for (int w = 1; w < 16; ++w) {
                const float ov = s_val[w];
                const int   oi = s_idx[w];
                const bool better = (ov > bv) || (ov == bv && oi < bi);
                bv = better ? ov : bv;
                bi = better ? oi : bi;
            }
            s_far = bi;
        }
        __syncthreads();

        // ---- owner thread broadcasts next centroid coords (reg -> LDS) ----
        {
            const int nf = s_far;
            if ((nf & (T - 1)) == t) {
                const int jj = nf >> 10;
                float x = px[0], y = py[0], z = pz[0];
#pragma unroll
                for (int k = 1; k < SLOTS; ++k) {
                    const bool c = (jj == k);
                    x = c ? px[k] : x;
                    y = c ? py[k] : y;
                    z = c ? pz[k] : z;
                }
                s_cx = x; s_cy = y; s_cz = z;
            }
        }
        __syncthreads();
    }
}

// ---------------------------------------------------------------------------
// Gather kernel: one wave64 per output row (64 channels). Reads the stored
// index (int at channel 0 of the row), then copies the full input row.
// ---------------------------------------------------------------------------
__global__ __launch_bounds__(256) void gather_kernel(const float* __restrict__ in,
                                                     float* out) {
    const int gid  = blockIdx.x * blockDim.x + threadIdx.x;
    const int row  = gid >> 6;     // 0 .. B*NC-1
    const int lane = gid & 63;     // channel
    const int b = row >> 12;       // NC == 4096
    const int idx = reinterpret_cast<const int*>(out)[(size_t)row * CC];
    const float v = in[((size_t)b * NN + idx) * CC + lane];
    out[(size_t)row * CC + lane] = v;
}

extern "C" void kernel_launch(void* const* d_in, const int* in_sizes, int n_in,
                              void* d_out, int out_size, void* d_ws, size_t ws_size,
                              hipStream_t stream) {
    const float* in = (const float*)d_in[0];
    float* out = (float*)d_out;

    fps_kernel<<<BB, T, 0, stream>>>(in, out);

    const int total = BB * NC * CC;          // 8,388,608
    gather_kernel<<<total / 256, 256, 0, stream>>>(in, out);
}

// Round 7
// 6681.010 us; speedup vs baseline: 1.4880x; 1.4880x over previous
//
#include <hip/hip_runtime.h>

#define BB 32
#define NN 16384
#define CC 64
#define NC 4096
#define T  1024          // threads per FPS block
#define SLOTS (NN / T)   // 16 points per thread

// ---------------------------------------------------------------------------
// FPS kernel: one block per batch element. Points + running dists in regs.
// Distance chain B1 = fma(dz,dz, fma(dx,dx, dy*dy)) — verified bitwise vs
// reference (R6 pass, absmax 0.0). contract(off) prevents other contraction.
//
// R7 changes (perf only, arithmetic identical):
//  - __launch_bounds__(1024,4): VGPR cap 128 (was 48 -> AGPR shuffling of
//    the 64-float register state; profile showed inflated VALU issue).
//  - max-VALUE-only tracking in the update loop (no per-point cmp/cndmask
//    index pair); matching threads rescan their 16 slots post-hoc and
//    atomicMin into LDS (descending-j select = first-occurrence ties,
//    atomicMin across threads = lowest global index — numpy argmax).
//  - no serial thread-0 reduce: all threads redundantly max the 16 wave
//    partials (LDS broadcast reads); parity double-buffered s_far2 so the
//    reset needs no extra barrier. 3 barriers/iter.
// ---------------------------------------------------------------------------
__global__ __launch_bounds__(T, 4) void fps_kernel(const float* __restrict__ in,
                                                   float* __restrict__ out) {
#pragma clang fp contract(off)
    const int b    = blockIdx.x;
    const int t    = threadIdx.x;
    const int wave = t >> 6;
    const int lane = t & 63;

    __shared__ float s_wmax[16];
    __shared__ float s_cx, s_cy, s_cz;
    __shared__ int   s_far2[2];

    const float* base = in + (size_t)b * NN * CC;

    float px[SLOTS], py[SLOTS], pz[SLOTS], dist[SLOTS];
#pragma unroll
    for (int j = 0; j < SLOTS; ++j) {
        const int i = j * T + t;
        const float4 v = *reinterpret_cast<const float4*>(base + (size_t)i * CC);
        px[j] = v.x; py[j] = v.y; pz[j] = v.z;
        dist[j] = 1e10f;
    }
    if (t == 0) { s_far2[0] = 0x7fffffff; s_far2[1] = 0x7fffffff; }

    // initial centroid = point 0 (uniform broadcast load)
    float cx = base[0], cy = base[1], cz = base[2];
    int   far = 0;
    __syncthreads();

    int* idx_out = reinterpret_cast<int*>(out);

    for (int it = 0; it < NC; ++it) {
        if (t == 0) idx_out[((size_t)b * NC + it) * CC] = far;
        if (it == NC - 1) break;

        // ---- dist update, value-max only (paired for max3/SLP fusion) ----
        float lv = -1.0f;
#pragma unroll
        for (int j = 0; j < SLOTS; j += 2) {
            const float dx0 = px[j]     - cx, dy0 = py[j]     - cy, dz0 = pz[j]     - cz;
            const float dx1 = px[j + 1] - cx, dy1 = py[j + 1] - cy, dz1 = pz[j + 1] - cz;
            const float d0  = fmaf(dz0, dz0, fmaf(dx0, dx0, dy0 * dy0));   // chain B1
            const float d1  = fmaf(dz1, dz1, fmaf(dx1, dx1, dy1 * dy1));
            const float n0  = fminf(dist[j],     d0);
            const float n1  = fminf(dist[j + 1], d1);
            dist[j] = n0; dist[j + 1] = n1;
            lv = fmaxf(lv, fmaxf(n0, n1));
        }

        // ---- wave64 value-max reduce ----
        float wv = lv;
#pragma unroll
        for (int off = 32; off > 0; off >>= 1)
            wv = fmaxf(wv, __shfl_down(wv, off));
        if (lane == 0) s_wmax[wave] = wv;
        if (t == 0) s_far2[(it + 1) & 1] = 0x7fffffff;   // prep next parity buffer
        __syncthreads();                                  // A

        // ---- redundant all-thread block max (broadcast LDS reads) ----
        const float m0 = fmaxf(fmaxf(s_wmax[0],  s_wmax[1]),  fmaxf(s_wmax[2],  s_wmax[3]));
        const float m1 = fmaxf(fmaxf(s_wmax[4],  s_wmax[5]),  fmaxf(s_wmax[6],  s_wmax[7]));
        const float m2 = fmaxf(fmaxf(s_wmax[8],  s_wmax[9]),  fmaxf(s_wmax[10], s_wmax[11]));
        const float m3 = fmaxf(fmaxf(s_wmax[12], s_wmax[13]), fmaxf(s_wmax[14], s_wmax[15]));
        const float gmax = fmaxf(fmaxf(m0, m1), fmaxf(m2, m3));

        // ---- matching threads find first local index, atomicMin for global ----
        if (lv == gmax) {
            int myi = 0x7fffffff;
#pragma unroll
            for (int j = SLOTS - 1; j >= 0; --j)         // descending: keep smallest j
                myi = (dist[j] == gmax) ? (j * T + t) : myi;
            atomicMin(&s_far2[it & 1], myi);
        }
        __syncthreads();                                  // B

        far = s_far2[it & 1];

        // ---- owner thread publishes next centroid coords ----
        if ((far & (T - 1)) == t) {
            const int jj = far >> 10;
            float x = px[0], y = py[0], z = pz[0];
#pragma unroll
            for (int k = 1; k < SLOTS; ++k) {
                const bool c = (jj == k);
                x = c ? px[k] : x;
                y = c ? py[k] : y;
                z = c ? pz[k] : z;
            }
            s_cx = x; s_cy = y; s_cz = z;
        }
        __syncthreads();                                  // C
        cx = s_cx; cy = s_cy; cz = s_cz;
    }
}

// ---------------------------------------------------------------------------
// Gather kernel: one wave64 per output row (64 channels). Reads the stored
// index (int at channel 0 of the row), then copies the full input row.
// ---------------------------------------------------------------------------
__global__ __launch_bounds__(256) void gather_kernel(const float* __restrict__ in,
                                                     float* out) {
    const int gid  = blockIdx.x * blockDim.x + threadIdx.x;
    const int row  = gid >> 6;     // 0 .. B*NC-1
    const int lane = gid & 63;     // channel
    const int b = row >> 12;       // NC == 4096
    const int idx = reinterpret_cast<const int*>(out)[(size_t)row * CC];
    const float v = in[((size_t)b * NN + idx) * CC + lane];
    out[(size_t)row * CC + lane] = v;
}

extern "C" void kernel_launch(void* const* d_in, const int* in_sizes, int n_in,
                              void* d_out, int out_size, void* d_ws, size_t ws_size,
                              hipStream_t stream) {
    const float* in = (const float*)d_in[0];
    float* out = (float*)d_out;

    fps_kernel<<<BB, T, 0, stream>>>(in, out);

    const int total = BB * NC * CC;          // 8,388,608
    gather_kernel<<<total / 256, 256, 0, stream>>>(in, out);
}